// Round 1
// baseline (740.148 us; speedup 1.0000x reference)
//
#include <hip/hip_runtime.h>

#define LL 512
#define DIMV 128
#define AD 64
#define KK 32

typedef __attribute__((ext_vector_type(8))) short bf16x8;
typedef __attribute__((ext_vector_type(4))) float f32x4;
typedef __attribute__((ext_vector_type(4))) unsigned short u16x4;
typedef __attribute__((ext_vector_type(8))) unsigned short u16x8;

__device__ __forceinline__ unsigned short f2bf(float f){
  unsigned u = __builtin_bit_cast(unsigned, f);
  u += 0x7FFFu + ((u >> 16) & 1u);          // RNE
  return (unsigned short)(u >> 16);
}
__device__ __forceinline__ float bf2f(unsigned short h){
  unsigned u = ((unsigned)h) << 16;
  return __builtin_bit_cast(float, u);
}

// ---------- coverage partial sums ----------
__global__ __launch_bounds__(256) void kcov(const float* __restrict__ td, float* __restrict__ part){
  __shared__ float red[256];
  int t = threadIdx.x;
  float s = 0.f;
  for (int idx = blockIdx.x*256 + t; idx < LL*LL; idx += 256*256)
    s += (td[idx] > 0.f) ? 1.f : 0.f;
  red[t] = s; __syncthreads();
  for (int st = 128; st > 0; st >>= 1){ if (t < st) red[t] += red[t+st]; __syncthreads(); }
  if (t == 0) part[blockIdx.x] = red[0];
}

// ---------- gate MLP + build transposed bf16 [Wq|Wg] (192 cols x 128 k) ----------
__global__ __launch_bounds__(256) void kgate(const float* __restrict__ part, const float* __restrict__ tq,
                      const float* __restrict__ W1, const float* __restrict__ b1,
                      const float* __restrict__ W2, const float* __restrict__ b2,
                      const float* __restrict__ Wq, const float* __restrict__ Wg,
                      float* __restrict__ gate_out, unsigned short* __restrict__ BT){
  int t = threadIdx.x;
  for (int idx = t; idx < 192*128; idx += 256){
    int c = idx >> 7, k = idx & 127;
    float w = (c < 64) ? Wq[k*64 + c] : Wg[k*128 + (c-64)];
    BT[c*128 + k] = f2bf(w);
  }
  __shared__ float red[256];
  red[t] = part[t]; __syncthreads();
  for (int st = 128; st > 0; st >>= 1){ if (t < st) red[t] += red[t+st]; __syncthreads(); }
  if (t == 0){
    float coverage = red[0] / (float)(LL*LL);
    float quality  = tq[0];
    float lennorm  = 1.0f;                   // 512/512
    float sacc = 0.f;
    for (int j = 0; j < 16; j++){
      float hv = coverage*W1[0*16+j] + quality*W1[1*16+j] + lennorm*W1[2*16+j] + b1[j];
      hv = hv > 0.f ? hv : 0.f;
      sacc += hv * W2[j];
    }
    gate_out[0] = 1.f / (1.f + __expf(-(sacc + b2[0])));
  }
}

// ---------- projections: left/rightT (bf16) and Wo-folded voL/voRT (bf16), t tables ----------
__global__ __launch_bounds__(256) void kproj(const float* __restrict__ pr, const float* __restrict__ td,
                      const int* __restrict__ anchor,
                      const float* __restrict__ Wl, const float* __restrict__ Wr,
                      const float* __restrict__ Wvl, const float* __restrict__ Wvr,
                      const float* __restrict__ Wo,
                      unsigned short* __restrict__ leftB, unsigned short* __restrict__ rightTB,
                      unsigned short* __restrict__ voLB, unsigned short* __restrict__ voRTB,
                      float* __restrict__ tl, float* __restrict__ tr){
  int side = blockIdx.x >> 9;                // 0: col side (i), 1: row side (j)
  int r    = blockIdx.x & 511;
  int w = threadIdx.x >> 6, lane = threadIdx.x & 63;
  __shared__ float sX[4][8][128];
  __shared__ float sV[4][8][64];
  const float* WL = side ? Wr  : Wl;
  const float* WV = side ? Wvr : Wvl;
  int kbase = w*8;
  for (int k8 = 0; k8 < 8; k8++){
    int ak = anchor[kbase + k8];
    const float* x = side ? (pr + ((size_t)ak*LL + r)*DIMV) : (pr + ((size_t)r*LL + ak)*DIMV);
    sX[w][k8][lane]      = x[lane];
    sX[w][k8][lane + 64] = x[lane + 64];
  }
  if (lane < 8){
    int k = kbase + lane;
    int ak = anchor[k];
    float tv = side ? td[(size_t)ak*LL + r] : td[(size_t)r*LL + ak];
    (side ? tr : tl)[r*KK + k] = tv;
  }
  __syncthreads();
  float accL[8], accV[8];
  #pragma unroll
  for (int k8 = 0; k8 < 8; k8++){ accL[k8] = 0.f; accV[k8] = 0.f; }
  for (int d = 0; d < DIMV; d++){
    float wl = WL[d*AD + lane];
    float wv = WV[d*AD + lane];
    #pragma unroll
    for (int k8 = 0; k8 < 8; k8++){
      float xv = sX[w][k8][d];
      accL[k8] += xv*wl; accV[k8] += xv*wv;
    }
  }
  unsigned short* outLR = side ? rightTB : leftB;
  #pragma unroll
  for (int k8 = 0; k8 < 8; k8++){
    int k = kbase + k8;
    outLR[((size_t)r*KK + k)*AD + lane] = f2bf(accL[k8]);
    sV[w][k8][lane] = accV[k8];
  }
  __syncthreads();
  float accO[8][2];
  #pragma unroll
  for (int k8 = 0; k8 < 8; k8++){ accO[k8][0] = 0.f; accO[k8][1] = 0.f; }
  for (int a = 0; a < AD; a++){
    float wo0 = Wo[a*DIMV + lane];
    float wo1 = Wo[a*DIMV + lane + 64];
    #pragma unroll
    for (int k8 = 0; k8 < 8; k8++){
      float vv = sV[w][k8][a];
      accO[k8][0] += vv*wo0; accO[k8][1] += vv*wo1;
    }
  }
  unsigned short* outVO = side ? voRTB : voLB;
  #pragma unroll
  for (int k8 = 0; k8 < 8; k8++){
    int k = kbase + k8;
    outVO[((size_t)r*KK + k)*DIMV + lane]      = f2bf(accO[k8][0]);
    outVO[((size_t)r*KK + k)*DIMV + lane + 64] = f2bf(accO[k8][1]);
  }
}

// ---------- MFMA GEMM: [262144 x 128] @ [128 x 192] -> q (64) | sigmoid(g)+bg (128) ----------
__global__ __launch_bounds__(256) void kqg(const float* __restrict__ pr, const unsigned short* __restrict__ BT,
                     const float* __restrict__ bg,
                     unsigned short* __restrict__ qB, unsigned short* __restrict__ gB){
  __shared__ unsigned short sBT[192*136];     // [col][k], pad 136 halfwords
  int t = threadIdx.x;
  for (int idx = t; idx < 192*16; idx += 256){
    int c = idx >> 4, k8 = idx & 15;
    *(u16x8*)(&sBT[c*136 + k8*8]) = *(const u16x8*)(BT + c*128 + k8*8);
  }
  __syncthreads();
  int w = t >> 6, lane = t & 63;
  int rrow = lane & 15, grp = lane >> 4;
  size_t row0 = (size_t)blockIdx.x*64 + w*16;
  const float* arow = pr + (row0 + rrow)*(size_t)DIMV + grp*8;
  float a[4][8];
  #pragma unroll
  for (int ks = 0; ks < 4; ks++){
    *(f32x4*)(&a[ks][0]) = *(const f32x4*)(arow + ks*32);
    *(f32x4*)(&a[ks][4]) = *(const f32x4*)(arow + ks*32 + 4);
  }
  f32x4 acc[12];
  f32x4 zero = {0.f, 0.f, 0.f, 0.f};
  #pragma unroll
  for (int ct = 0; ct < 12; ct++) acc[ct] = zero;
  #pragma unroll
  for (int ks = 0; ks < 4; ks++){
    bf16x8 af;
    #pragma unroll
    for (int e = 0; e < 8; e++) af[e] = (short)f2bf(a[ks][e]);
    #pragma unroll
    for (int ct = 0; ct < 12; ct++){
      bf16x8 bfr = *(const bf16x8*)(&sBT[(ct*16 + rrow)*136 + ks*32 + grp*8]);
      acc[ct] = __builtin_amdgcn_mfma_f32_16x16x32_bf16(af, bfr, acc[ct], 0, 0, 0);
    }
  }
  #pragma unroll
  for (int ct = 0; ct < 12; ct++){
    int col = ct*16 + rrow;                   // C/D: col = lane&15
    #pragma unroll
    for (int rg = 0; rg < 4; rg++){
      size_t grow = row0 + grp*4 + rg;        // C/D: row = (lane>>4)*4 + reg
      float v = acc[ct][rg];
      if (col < 64){
        qB[grow*AD + col] = f2bf(v);
      } else {
        int e = col - 64;
        float s = 1.f / (1.f + __expf(-(v + bg[e])));
        gB[grow*DIMV + e] = f2bf(s);
      }
    }
  }
}

// ---------- fused attention core + output ----------
__global__ __launch_bounds__(256) void kmain(
    const float* __restrict__ pr, const float* __restrict__ td,
    const unsigned short* __restrict__ qB, const unsigned short* __restrict__ gB,
    const unsigned short* __restrict__ leftB, const unsigned short* __restrict__ rightTB,
    const unsigned short* __restrict__ voLB, const unsigned short* __restrict__ voRTB,
    const float* __restrict__ tl, const float* __restrict__ tr,
    const float* __restrict__ gatep,
    float* __restrict__ out){
  __shared__ unsigned short sBig[2*4*32*132]; // phase1: sL/sR stride68; phase2: sVL/sVR stride132
  __shared__ float sAttn[16][32];
  __shared__ float sQ[4][64];
  int i0 = blockIdx.y*4, j0 = blockIdx.x*4;
  int t = threadIdx.x, w = t >> 6, lane = t & 63;
  float gate = gatep[0];

  unsigned short* sL = sBig;
  unsigned short* sR = sBig + 4*32*68;
  for (int idx = t; idx < 2048; idx += 256){  // 4*32*64/4 chunks per matrix
    int rk = idx >> 4, a4 = idx & 15;
    *(u16x4*)(&sL[rk*68 + a4*4]) = *(const u16x4*)(leftB   + ((size_t)i0*KK + rk)*AD + a4*4);
    *(u16x4*)(&sR[rk*68 + a4*4]) = *(const u16x4*)(rightTB + ((size_t)j0*KK + rk)*AD + a4*4);
  }
  __syncthreads();
  int k = lane & 31, h = lane >> 5;
  for (int pp = 0; pp < 4; pp++){
    int p = w*4 + pp, ti = p >> 2, tj = p & 3;
    int i = i0 + ti, j = j0 + tj;
    sQ[w][lane] = bf2f(qB[((size_t)i*LL + j)*AD + lane]);
    const unsigned short* pL = sL + (ti*KK + k)*68 + h*32;
    const unsigned short* pR = sR + (tj*KK + k)*68 + h*32;
    const float* pQ = &sQ[w][h*32];
    float sp = 0.f;
    #pragma unroll
    for (int a = 0; a < 32; a++)
      sp += pQ[a] * (bf2f(pL[a]) + bf2f(pR[a]));
    sp += __shfl_xor(sp, 32);
    float sc = sp * 0.125f;
    float tb = tl[(size_t)i*KK + k] + tr[(size_t)j*KK + k] - td[(size_t)i*LL + j];
    sc -= gate * fabsf(tb) * 0.25f;
    float m = sc;
    #pragma unroll
    for (int st = 16; st >= 1; st >>= 1) m = fmaxf(m, __shfl_xor(m, st));
    float e = __expf(sc - m);
    float ss = e;
    #pragma unroll
    for (int st = 16; st >= 1; st >>= 1) ss += __shfl_xor(ss, st);
    if (lane < 32) sAttn[p][k] = e / ss;
  }
  __syncthreads();
  unsigned short* sVL = sBig;
  unsigned short* sVR = sBig + 4*32*132;
  for (int idx = t; idx < 4096; idx += 256){  // 4*32*128/4 chunks per matrix
    int rk = idx >> 5, d4 = idx & 31;
    *(u16x4*)(&sVL[rk*132 + d4*4]) = *(const u16x4*)(voLB  + ((size_t)i0*KK + rk)*DIMV + d4*4);
    *(u16x4*)(&sVR[rk*132 + d4*4]) = *(const u16x4*)(voRTB + ((size_t)j0*KK + rk)*DIMV + d4*4);
  }
  __syncthreads();
  for (int pp = 0; pp < 4; pp++){
    int p = w*4 + pp, ti = p >> 2, tj = p & 3;
    size_t pi = (size_t)(i0 + ti)*LL + (j0 + tj);
    const float* pA = sAttn[p];
    const unsigned short* pVL = sVL + (size_t)ti*KK*132;
    const unsigned short* pVR = sVR + (size_t)tj*KK*132;
    float u0 = 0.f, u1 = 0.f;
    #pragma unroll
    for (int kk = 0; kk < 32; kk++){
      float av = pA[kk];
      u0 += av * (bf2f(pVL[kk*132 + lane])      + bf2f(pVR[kk*132 + lane]));
      u1 += av * (bf2f(pVL[kk*132 + lane + 64]) + bf2f(pVR[kk*132 + lane + 64]));
    }
    float g0 = bf2f(gB[pi*DIMV + lane]);
    float g1 = bf2f(gB[pi*DIMV + lane + 64]);
    float x0 = pr[pi*DIMV + lane];
    float x1 = pr[pi*DIMV + lane + 64];
    out[pi*DIMV + lane]      = x0 + g0*u0;
    out[pi*DIMV + lane + 64] = x1 + g1*u1;
  }
}

extern "C" void kernel_launch(void* const* d_in, const int* in_sizes, int n_in,
                              void* d_out, int out_size, void* d_ws, size_t ws_size,
                              hipStream_t stream){
  const float* pr  = (const float*)d_in[0];
  const float* td  = (const float*)d_in[1];
  const float* tq  = (const float*)d_in[2];
  const float* Wq  = (const float*)d_in[3];
  const float* Wl  = (const float*)d_in[4];
  const float* Wr  = (const float*)d_in[5];
  const float* Wvl = (const float*)d_in[6];
  const float* Wvr = (const float*)d_in[7];
  const float* Wo  = (const float*)d_in[8];
  const float* Wg  = (const float*)d_in[9];
  const float* bg  = (const float*)d_in[10];
  const float* W1  = (const float*)d_in[11];
  const float* b1  = (const float*)d_in[12];
  const float* W2  = (const float*)d_in[13];
  const float* b2  = (const float*)d_in[14];
  const int* anchor = (const int*)d_in[15];
  float* out = (float*)d_out;

  char* ws = (char*)d_ws;
  size_t off = 0;
  auto alloc = [&](size_t bytes)->void*{ void* p = ws + off; off += (bytes + 255) & ~(size_t)255; return p; };
  float* g_gate  = (float*)alloc(4);
  float* g_part  = (float*)alloc(256*4);
  float* g_tl    = (float*)alloc((size_t)LL*KK*4);
  float* g_tr    = (float*)alloc((size_t)LL*KK*4);
  unsigned short* g_BT     = (unsigned short*)alloc((size_t)192*128*2);
  unsigned short* g_left   = (unsigned short*)alloc((size_t)LL*KK*AD*2);
  unsigned short* g_rightT = (unsigned short*)alloc((size_t)LL*KK*AD*2);
  unsigned short* g_voL    = (unsigned short*)alloc((size_t)LL*KK*DIMV*2);
  unsigned short* g_voRT   = (unsigned short*)alloc((size_t)LL*KK*DIMV*2);
  unsigned short* g_q      = (unsigned short*)alloc((size_t)LL*LL*AD*2);
  unsigned short* g_g      = (unsigned short*)alloc((size_t)LL*LL*DIMV*2);
  (void)ws_size; (void)in_sizes; (void)n_in; (void)out_size;

  kcov <<<256, 256, 0, stream>>>(td, g_part);
  kgate<<<1,   256, 0, stream>>>(g_part, tq, W1, b1, W2, b2, Wq, Wg, g_gate, g_BT);
  kproj<<<1024,256, 0, stream>>>(pr, td, anchor, Wl, Wr, Wvl, Wvr, Wo,
                                 g_left, g_rightT, g_voL, g_voRT, g_tl, g_tr);
  kqg  <<<4096,256, 0, stream>>>(pr, g_BT, bg, g_q, g_g);
  kmain<<<dim3(128,128), 256, 0, stream>>>(pr, td, g_q, g_g, g_left, g_rightT,
                                           g_voL, g_voRT, g_tl, g_tr, g_gate, out);
}

// Round 2
// 310.670 us; speedup vs baseline: 2.3824x; 2.3824x over previous
//
#include <hip/hip_runtime.h>

#define LL 512
#define DIMV 128
#define AD 64
#define KK 32

#define S_I 530   // f32 stride per i in S
#define S_J 33    // f32 stride per j in S
#define U_I 2116  // u16 stride per i in U1
#define U_J 132   // u16 stride per j in U1

typedef __attribute__((ext_vector_type(8))) short bf16x8;
typedef __attribute__((ext_vector_type(4))) float f32x4;
typedef __attribute__((ext_vector_type(4))) unsigned short u16x4;
typedef __attribute__((ext_vector_type(8))) unsigned short u16x8;

#define MFMA(a,b,c) __builtin_amdgcn_mfma_f32_16x16x32_bf16(a,b,c,0,0,0)

__device__ __forceinline__ unsigned short f2bf(float f){
  unsigned u = __builtin_bit_cast(unsigned, f);
  u += 0x7FFFu + ((u >> 16) & 1u);          // RNE
  return (unsigned short)(u >> 16);
}
__device__ __forceinline__ float bf2f(unsigned short h){
  unsigned u = ((unsigned)h) << 16;
  return __builtin_bit_cast(float, u);
}

// ---------- coverage partial sums ----------
__global__ __launch_bounds__(256) void kcov(const float* __restrict__ td, float* __restrict__ part){
  __shared__ float red[256];
  int t = threadIdx.x;
  float s = 0.f;
  for (int idx = blockIdx.x*256 + t; idx < LL*LL; idx += 256*256)
    s += (td[idx] > 0.f) ? 1.f : 0.f;
  red[t] = s; __syncthreads();
  for (int st = 128; st > 0; st >>= 1){ if (t < st) red[t] += red[t+st]; __syncthreads(); }
  if (t == 0) part[blockIdx.x] = red[0];
}

// ---------- gate MLP ----------
__global__ __launch_bounds__(256) void kgate(const float* __restrict__ part, const float* __restrict__ tq,
                      const float* __restrict__ W1, const float* __restrict__ b1,
                      const float* __restrict__ W2, const float* __restrict__ b2,
                      const float* __restrict__ Wq, const float* __restrict__ Wg,
                      float* __restrict__ gate_out, unsigned short* __restrict__ BT){
  int t = threadIdx.x;
  for (int idx = t; idx < 192*128; idx += 256){
    int c = idx >> 7, k = idx & 127;
    float w = (c < 64) ? Wq[k*64 + c] : Wg[k*128 + (c-64)];
    BT[c*128 + k] = f2bf(w);
  }
  __shared__ float red[256];
  red[t] = part[t]; __syncthreads();
  for (int st = 128; st > 0; st >>= 1){ if (t < st) red[t] += red[t+st]; __syncthreads(); }
  if (t == 0){
    float coverage = red[0] / (float)(LL*LL);
    float quality  = tq[0];
    float lennorm  = 1.0f;
    float sacc = 0.f;
    for (int j = 0; j < 16; j++){
      float hv = coverage*W1[0*16+j] + quality*W1[1*16+j] + lennorm*W1[2*16+j] + b1[j];
      hv = hv > 0.f ? hv : 0.f;
      sacc += hv * W2[j];
    }
    gate_out[0] = 1.f / (1.f + __expf(-(sacc + b2[0])));
  }
}

// ---------- projections: left/rightT natural [r][k][a]; voLT/voRTT transposed [r][d][k] ----------
__global__ __launch_bounds__(256) void kproj(const float* __restrict__ pr, const float* __restrict__ td,
                      const int* __restrict__ anchor,
                      const float* __restrict__ Wl, const float* __restrict__ Wr,
                      const float* __restrict__ Wvl, const float* __restrict__ Wvr,
                      const float* __restrict__ Wo,
                      unsigned short* __restrict__ leftB, unsigned short* __restrict__ rightTB,
                      unsigned short* __restrict__ voLT, unsigned short* __restrict__ voRTT,
                      float* __restrict__ tl, float* __restrict__ tr){
  int side = blockIdx.x >> 9;                // 0: col side (i), 1: row side (j)
  int r    = blockIdx.x & 511;
  int t = threadIdx.x, w = t >> 6, lane = t & 63;
  __shared__ float sX[32][128];
  __shared__ float sV[32][65];
  __shared__ float sWo[64][128];
  const float* WL = side ? Wr  : Wl;
  const float* WV = side ? Wvr : Wvl;
  for (int idx = t; idx < 64*128; idx += 256) sWo[idx>>7][idx&127] = Wo[idx];
  int kbase = w*8;
  for (int k8 = 0; k8 < 8; k8++){
    int ak = anchor[kbase + k8];
    const float* x = side ? (pr + ((size_t)ak*LL + r)*DIMV) : (pr + ((size_t)r*LL + ak)*DIMV);
    sX[kbase+k8][lane]    = x[lane];
    sX[kbase+k8][lane+64] = x[lane + 64];
  }
  if (lane < 8){
    int k = kbase + lane;
    int ak = anchor[k];
    float tv = side ? td[(size_t)ak*LL + r] : td[(size_t)r*LL + ak];
    (side ? tr : tl)[r*KK + k] = tv;
  }
  __syncthreads();
  float accL[8], accV[8];
  #pragma unroll
  for (int k8 = 0; k8 < 8; k8++){ accL[k8] = 0.f; accV[k8] = 0.f; }
  for (int d = 0; d < DIMV; d++){
    float wl = WL[d*AD + lane];
    float wv = WV[d*AD + lane];
    #pragma unroll
    for (int k8 = 0; k8 < 8; k8++){
      float xv = sX[kbase+k8][d];
      accL[k8] += xv*wl; accV[k8] += xv*wv;
    }
  }
  unsigned short* outLR = side ? rightTB : leftB;
  #pragma unroll
  for (int k8 = 0; k8 < 8; k8++){
    int k = kbase + k8;
    outLR[((size_t)r*KK + k)*AD + lane] = f2bf(accL[k8]);
    sV[k][lane] = accV[k8];
  }
  __syncthreads();
  // phase2: voT[d][k] = sum_a sV[k][a] * Wo[a][d], thread -> (k = t&31, dgroup = t>>5)
  int k = t & 31, dg = t >> 5;
  f32x4 acc4[4];
  f32x4 zf = {0.f,0.f,0.f,0.f};
  #pragma unroll
  for (int q = 0; q < 4; q++) acc4[q] = zf;
  for (int a = 0; a < AD; a++){
    float va = sV[k][a];
    #pragma unroll
    for (int q = 0; q < 4; q++)
      acc4[q] += (*(const f32x4*)&sWo[a][dg*16 + q*4]) * va;
  }
  unsigned short* outV = side ? voRTT : voLT;
  #pragma unroll
  for (int q = 0; q < 4; q++)
    #pragma unroll
    for (int e = 0; e < 4; e++){
      int d = dg*16 + q*4 + e;
      outV[((size_t)r*DIMV + d)*KK + k] = f2bf(acc4[q][e]);
    }
}

// ---------- MFMA GEMM: q (64) | sigmoid(g)+bg (128) ----------
__global__ __launch_bounds__(256) void kqg(const float* __restrict__ pr, const unsigned short* __restrict__ BT,
                     const float* __restrict__ bg,
                     unsigned short* __restrict__ qB, unsigned short* __restrict__ gB){
  __shared__ unsigned short sBT[192*136];
  int t = threadIdx.x;
  for (int idx = t; idx < 192*16; idx += 256){
    int c = idx >> 4, k8 = idx & 15;
    *(u16x8*)(&sBT[c*136 + k8*8]) = *(const u16x8*)(BT + c*128 + k8*8);
  }
  __syncthreads();
  int w = t >> 6, lane = t & 63;
  int rrow = lane & 15, grp = lane >> 4;
  size_t row0 = (size_t)blockIdx.x*64 + w*16;
  const float* arow = pr + (row0 + rrow)*(size_t)DIMV + grp*8;
  float a[4][8];
  #pragma unroll
  for (int ks = 0; ks < 4; ks++){
    *(f32x4*)(&a[ks][0]) = *(const f32x4*)(arow + ks*32);
    *(f32x4*)(&a[ks][4]) = *(const f32x4*)(arow + ks*32 + 4);
  }
  f32x4 acc[12];
  f32x4 zero = {0.f, 0.f, 0.f, 0.f};
  #pragma unroll
  for (int ct = 0; ct < 12; ct++) acc[ct] = zero;
  #pragma unroll
  for (int ks = 0; ks < 4; ks++){
    bf16x8 af;
    #pragma unroll
    for (int e = 0; e < 8; e++) af[e] = (short)f2bf(a[ks][e]);
    #pragma unroll
    for (int ct = 0; ct < 12; ct++){
      bf16x8 bfr = *(const bf16x8*)(&sBT[(ct*16 + rrow)*136 + ks*32 + grp*8]);
      acc[ct] = MFMA(af, bfr, acc[ct]);
    }
  }
  #pragma unroll
  for (int ct = 0; ct < 12; ct++){
    int col = ct*16 + rrow;
    #pragma unroll
    for (int rg = 0; rg < 4; rg++){
      size_t grow = row0 + grp*4 + rg;
      float v = acc[ct][rg];
      if (col < 64){
        qB[grow*AD + col] = f2bf(v);
      } else {
        int e = col - 64;
        float s = 1.f / (1.f + __expf(-(v + bg[e])));
        gB[grow*DIMV + e] = f2bf(s);
      }
    }
  }
}

// ---------- fused attention core (MFMA) ----------
__global__ __launch_bounds__(512) void kmain(
    const float* __restrict__ pr, const float* __restrict__ td,
    const unsigned short* __restrict__ qB, const unsigned short* __restrict__ gB,
    const unsigned short* __restrict__ leftB, const unsigned short* __restrict__ rightTB,
    const unsigned short* __restrict__ voLT, const unsigned short* __restrict__ voRTT,
    const float* __restrict__ tl, const float* __restrict__ tr,
    const float* __restrict__ gatep,
    float* __restrict__ out){
  __shared__ __align__(16) char smem[67712];
  float* S = (float*)smem;                    // [16i][16j][32k], strides S_I/S_J
  unsigned short* U1 = (unsigned short*)smem; // [16i][16j][128d], strides U_I/U_J (aliased)
  const int i0 = blockIdx.y*16, j0 = blockIdx.x*16;
  const int t = threadIdx.x, w = t >> 6, lane = t & 63;
  const int n = lane & 15, grp = lane >> 4;
  const float gate = gatep[0];
  const f32x4 zf = {0.f,0.f,0.f,0.f};

  // ---- term1: wave w handles i = 2w, 2w+1 ----
  #pragma unroll
  for (int ii = 0; ii < 2; ii++){
    int i = w*2 + ii;
    const unsigned short* qp = qB + (((size_t)(i0+i)*LL) + j0 + n)*AD + grp*8;
    bf16x8 a0 = *(const bf16x8*)qp;
    bf16x8 a1 = *(const bf16x8*)(qp + 32);
    const unsigned short* lp = leftB + (((size_t)(i0+i)*KK) + n)*AD + grp*8;
    f32x4 acc0 = zf, acc1 = zf;
    acc0 = MFMA(a0, *(const bf16x8*)(lp),            acc0);
    acc0 = MFMA(a1, *(const bf16x8*)(lp + 32),       acc0);
    acc1 = MFMA(a0, *(const bf16x8*)(lp + 16*AD),    acc1);
    acc1 = MFMA(a1, *(const bf16x8*)(lp + 16*AD+32), acc1);
    #pragma unroll
    for (int r2 = 0; r2 < 4; r2++){
      S[i*S_I + (grp*4+r2)*S_J + n]      = acc0[r2];
      S[i*S_I + (grp*4+r2)*S_J + 16 + n] = acc1[r2];
    }
  }
  __syncthreads();
  // ---- term2 + bias: wave w handles j = 2w, 2w+1 ----
  #pragma unroll
  for (int jj = 0; jj < 2; jj++){
    int j = w*2 + jj;
    const unsigned short* qp = qB + (((size_t)(i0+n)*LL) + j0 + j)*AD + grp*8;
    bf16x8 a0 = *(const bf16x8*)qp;
    bf16x8 a1 = *(const bf16x8*)(qp + 32);
    const unsigned short* rp = rightTB + (((size_t)(j0+j)*KK) + n)*AD + grp*8;
    f32x4 acc0 = zf, acc1 = zf;
    acc0 = MFMA(a0, *(const bf16x8*)(rp),            acc0);
    acc0 = MFMA(a1, *(const bf16x8*)(rp + 32),       acc0);
    acc1 = MFMA(a0, *(const bf16x8*)(rp + 16*AD),    acc1);
    acc1 = MFMA(a1, *(const bf16x8*)(rp + 16*AD+32), acc1);
    #pragma unroll
    for (int r2 = 0; r2 < 4; r2++){
      int i = grp*4 + r2;
      float tdv = td[((size_t)(i0+i))*LL + j0 + j];
      #pragma unroll
      for (int nt = 0; nt < 2; nt++){
        int k = nt*16 + n;
        float acc = nt ? acc1[r2] : acc0[r2];
        float tb = tl[(i0+i)*KK + k] + tr[(j0+j)*KK + k] - tdv;
        int idx = i*S_I + j*S_J + k;
        S[idx] = (S[idx] + acc)*0.125f - gate*0.25f*fabsf(tb);
      }
    }
  }
  __syncthreads();
  // ---- softmax: 2 threads per (i,j) pair ----
  {
    int pair = t >> 1, half = t & 1;
    int i = pair >> 4, j = pair & 15;
    float* row = S + i*S_I + j*S_J + half*16;
    float v[16];
    float m = -1e30f;
    #pragma unroll
    for (int kk = 0; kk < 16; kk++){ v[kk] = row[kk]; m = fmaxf(m, v[kk]); }
    m = fmaxf(m, __shfl_xor(m, 1));
    float ss = 0.f;
    #pragma unroll
    for (int kk = 0; kk < 16; kk++){ v[kk] = __expf(v[kk] - m); ss += v[kk]; }
    ss += __shfl_xor(ss, 1);
    float rr = 1.0f / ss;
    #pragma unroll
    for (int kk = 0; kk < 16; kk++) row[kk] = v[kk]*rr;
  }
  __syncthreads();
  // ---- load PV A-frags (attn) before LDS reuse ----
  bf16x8 pa1[2], pa2[2];
  #pragma unroll
  for (int ii = 0; ii < 2; ii++){
    int i = w*2 + ii;
    #pragma unroll
    for (int e = 0; e < 8; e++) pa1[ii][e] = (short)f2bf(S[i*S_I + n*S_J + grp*8 + e]);
    #pragma unroll
    for (int e = 0; e < 8; e++) pa2[ii][e] = (short)f2bf(S[n*S_I + i*S_J + grp*8 + e]);
  }
  __syncthreads();
  // ---- PV1: U1[i][j][d] (bf16) ----
  #pragma unroll
  for (int ii = 0; ii < 2; ii++){
    int i = w*2 + ii;
    #pragma unroll
    for (int nt = 0; nt < 8; nt++){
      bf16x8 bv = *(const bf16x8*)(voLT + (((size_t)(i0+i)*DIMV) + nt*16 + n)*KK + grp*8);
      f32x4 acc = MFMA(pa1[ii], bv, zf);
      #pragma unroll
      for (int r2 = 0; r2 < 4; r2++)
        U1[i*U_I + (grp*4+r2)*U_J + nt*16 + n] = f2bf(acc[r2]);
    }
  }
  __syncthreads();
  // ---- PV2 + gate + residual + store ----
  #pragma unroll
  for (int jj = 0; jj < 2; jj++){
    int j = w*2 + jj;
    #pragma unroll
    for (int nt = 0; nt < 8; nt++){
      bf16x8 bv = *(const bf16x8*)(voRTT + (((size_t)(j0+j)*DIMV) + nt*16 + n)*KK + grp*8);
      f32x4 acc = MFMA(pa2[jj], bv, zf);
      #pragma unroll
      for (int r2 = 0; r2 < 4; r2++){
        int i = grp*4 + r2;
        int d = nt*16 + n;
        size_t pi = ((size_t)(i0+i)*LL + j0 + j);
        float u = acc[r2] + bf2f(U1[i*U_I + j*U_J + d]);
        float gg = bf2f(gB[pi*DIMV + d]);
        out[pi*DIMV + d] = pr[pi*DIMV + d] + gg*u;
      }
    }
  }
}

extern "C" void kernel_launch(void* const* d_in, const int* in_sizes, int n_in,
                              void* d_out, int out_size, void* d_ws, size_t ws_size,
                              hipStream_t stream){
  const float* pr  = (const float*)d_in[0];
  const float* td  = (const float*)d_in[1];
  const float* tq  = (const float*)d_in[2];
  const float* Wq  = (const float*)d_in[3];
  const float* Wl  = (const float*)d_in[4];
  const float* Wr  = (const float*)d_in[5];
  const float* Wvl = (const float*)d_in[6];
  const float* Wvr = (const float*)d_in[7];
  const float* Wo  = (const float*)d_in[8];
  const float* Wg  = (const float*)d_in[9];
  const float* bg  = (const float*)d_in[10];
  const float* W1  = (const float*)d_in[11];
  const float* b1  = (const float*)d_in[12];
  const float* W2  = (const float*)d_in[13];
  const float* b2  = (const float*)d_in[14];
  const int* anchor = (const int*)d_in[15];
  float* out = (float*)d_out;

  char* ws = (char*)d_ws;
  size_t off = 0;
  auto alloc = [&](size_t bytes)->void*{ void* p = ws + off; off += (bytes + 255) & ~(size_t)255; return p; };
  float* g_gate  = (float*)alloc(4);
  float* g_part  = (float*)alloc(256*4);
  float* g_tl    = (float*)alloc((size_t)LL*KK*4);
  float* g_tr    = (float*)alloc((size_t)LL*KK*4);
  unsigned short* g_BT     = (unsigned short*)alloc((size_t)192*128*2);
  unsigned short* g_left   = (unsigned short*)alloc((size_t)LL*KK*AD*2);
  unsigned short* g_rightT = (unsigned short*)alloc((size_t)LL*KK*AD*2);
  unsigned short* g_voLT   = (unsigned short*)alloc((size_t)LL*DIMV*KK*2);
  unsigned short* g_voRTT  = (unsigned short*)alloc((size_t)LL*DIMV*KK*2);
  unsigned short* g_q      = (unsigned short*)alloc((size_t)LL*LL*AD*2);
  unsigned short* g_g      = (unsigned short*)alloc((size_t)LL*LL*DIMV*2);
  (void)ws_size; (void)in_sizes; (void)n_in; (void)out_size;

  kcov <<<256, 256, 0, stream>>>(td, g_part);
  kgate<<<1,   256, 0, stream>>>(g_part, tq, W1, b1, W2, b2, Wq, Wg, g_gate, g_BT);
  kproj<<<1024,256, 0, stream>>>(pr, td, anchor, Wl, Wr, Wvl, Wvr, Wo,
                                 g_left, g_rightT, g_voLT, g_voRTT, g_tl, g_tr);
  kqg  <<<4096,256, 0, stream>>>(pr, g_BT, bg, g_q, g_g);
  kmain<<<dim3(32,32), 512, 0, stream>>>(pr, td, g_q, g_g, g_left, g_rightT,
                                         g_voLT, g_voRTT, g_tl, g_tr, g_gate, out);
}

// Round 3
// 264.303 us; speedup vs baseline: 2.8004x; 1.1754x over previous
//
#include <hip/hip_runtime.h>

#define LL 512
#define DIMV 128
#define AD 64
#define KK 32

#define S_I 530   // f32 stride per i in S
#define S_J 33    // f32 stride per j in S
#define U_I 2176  // u16 stride per i in U1 (16B aligned)
#define U_J 136   // u16 stride per j in U1 (16B aligned)

typedef __attribute__((ext_vector_type(8))) short bf16x8;
typedef __attribute__((ext_vector_type(4))) float f32x4;
typedef __attribute__((ext_vector_type(4))) unsigned short u16x4;
typedef __attribute__((ext_vector_type(8))) unsigned short u16x8;

#define MFMA(a,b,c) __builtin_amdgcn_mfma_f32_16x16x32_bf16(a,b,c,0,0,0)

__device__ __forceinline__ unsigned short f2bf(float f){
  unsigned u = __builtin_bit_cast(unsigned, f);
  u += 0x7FFFu + ((u >> 16) & 1u);          // RNE
  return (unsigned short)(u >> 16);
}
__device__ __forceinline__ float bf2f(unsigned short h){
  unsigned u = ((unsigned)h) << 16;
  return __builtin_bit_cast(float, u);
}

// ---------- coverage partial sums ----------
__global__ __launch_bounds__(256) void kcov(const float* __restrict__ td, float* __restrict__ part){
  __shared__ float red[256];
  int t = threadIdx.x;
  float s = 0.f;
  for (int idx = blockIdx.x*256 + t; idx < LL*LL; idx += 256*256)
    s += (td[idx] > 0.f) ? 1.f : 0.f;
  red[t] = s; __syncthreads();
  for (int st = 128; st > 0; st >>= 1){ if (t < st) red[t] += red[t+st]; __syncthreads(); }
  if (t == 0) part[blockIdx.x] = red[0];
}

// ---------- gate MLP ----------
__global__ __launch_bounds__(256) void kgate(const float* __restrict__ part, const float* __restrict__ tq,
                      const float* __restrict__ W1, const float* __restrict__ b1,
                      const float* __restrict__ W2, const float* __restrict__ b2,
                      const float* __restrict__ Wq, const float* __restrict__ Wg,
                      float* __restrict__ gate_out, unsigned short* __restrict__ BT){
  int t = threadIdx.x;
  for (int idx = t; idx < 192*128; idx += 256){
    int c = idx >> 7, k = idx & 127;
    float w = (c < 64) ? Wq[k*64 + c] : Wg[k*128 + (c-64)];
    BT[c*128 + k] = f2bf(w);
  }
  __shared__ float red[256];
  red[t] = part[t]; __syncthreads();
  for (int st = 128; st > 0; st >>= 1){ if (t < st) red[t] += red[t+st]; __syncthreads(); }
  if (t == 0){
    float coverage = red[0] / (float)(LL*LL);
    float quality  = tq[0];
    float lennorm  = 1.0f;
    float sacc = 0.f;
    for (int j = 0; j < 16; j++){
      float hv = coverage*W1[0*16+j] + quality*W1[1*16+j] + lennorm*W1[2*16+j] + b1[j];
      hv = hv > 0.f ? hv : 0.f;
      sacc += hv * W2[j];
    }
    gate_out[0] = 1.f / (1.f + __expf(-(sacc + b2[0])));
  }
}

// ---------- projections: left/rightT natural [r][k][a]; voLT/voRTT transposed [r][d][k] ----------
__global__ __launch_bounds__(256) void kproj(const float* __restrict__ pr, const float* __restrict__ td,
                      const int* __restrict__ anchor,
                      const float* __restrict__ Wl, const float* __restrict__ Wr,
                      const float* __restrict__ Wvl, const float* __restrict__ Wvr,
                      const float* __restrict__ Wo,
                      unsigned short* __restrict__ leftB, unsigned short* __restrict__ rightTB,
                      unsigned short* __restrict__ voLT, unsigned short* __restrict__ voRTT,
                      float* __restrict__ tl, float* __restrict__ tr){
  int side = blockIdx.x >> 9;                // 0: col side (i), 1: row side (j)
  int r    = blockIdx.x & 511;
  int t = threadIdx.x, w = t >> 6, lane = t & 63;
  __shared__ float sX[32][128];
  __shared__ float sV[32][65];
  __shared__ float sWo[64][128];
  const float* WL = side ? Wr  : Wl;
  const float* WV = side ? Wvr : Wvl;
  for (int idx = t; idx < 64*128; idx += 256) sWo[idx>>7][idx&127] = Wo[idx];
  int kbase = w*8;
  for (int k8 = 0; k8 < 8; k8++){
    int ak = anchor[kbase + k8];
    const float* x = side ? (pr + ((size_t)ak*LL + r)*DIMV) : (pr + ((size_t)r*LL + ak)*DIMV);
    sX[kbase+k8][lane]    = x[lane];
    sX[kbase+k8][lane+64] = x[lane + 64];
  }
  if (lane < 8){
    int k = kbase + lane;
    int ak = anchor[k];
    float tv = side ? td[(size_t)ak*LL + r] : td[(size_t)r*LL + ak];
    (side ? tr : tl)[r*KK + k] = tv;
  }
  __syncthreads();
  float accL[8], accV[8];
  #pragma unroll
  for (int k8 = 0; k8 < 8; k8++){ accL[k8] = 0.f; accV[k8] = 0.f; }
  for (int d = 0; d < DIMV; d++){
    float wl = WL[d*AD + lane];
    float wv = WV[d*AD + lane];
    #pragma unroll
    for (int k8 = 0; k8 < 8; k8++){
      float xv = sX[kbase+k8][d];
      accL[k8] += xv*wl; accV[k8] += xv*wv;
    }
  }
  unsigned short* outLR = side ? rightTB : leftB;
  #pragma unroll
  for (int k8 = 0; k8 < 8; k8++){
    int k = kbase + k8;
    outLR[((size_t)r*KK + k)*AD + lane] = f2bf(accL[k8]);
    sV[k][lane] = accV[k8];
  }
  __syncthreads();
  // phase2: voT[d][k] = sum_a sV[k][a] * Wo[a][d]
  int k = t & 31, dg = t >> 5;
  f32x4 acc4[4];
  f32x4 zf = {0.f,0.f,0.f,0.f};
  #pragma unroll
  for (int q = 0; q < 4; q++) acc4[q] = zf;
  for (int a = 0; a < AD; a++){
    float va = sV[k][a];
    #pragma unroll
    for (int q = 0; q < 4; q++)
      acc4[q] += (*(const f32x4*)&sWo[a][dg*16 + q*4]) * va;
  }
  unsigned short* outV = side ? voRTT : voLT;
  #pragma unroll
  for (int q = 0; q < 4; q++)
    #pragma unroll
    for (int e = 0; e < 4; e++){
      int d = dg*16 + q*4 + e;
      outV[((size_t)r*DIMV + d)*KK + k] = f2bf(acc4[q][e]);
    }
}

// ---------- MFMA GEMM: q (64) | sigmoid(g)+bg (128) ----------
__global__ __launch_bounds__(256) void kqg(const float* __restrict__ pr, const unsigned short* __restrict__ BT,
                     const float* __restrict__ bg,
                     unsigned short* __restrict__ qB, unsigned short* __restrict__ gB){
  __shared__ unsigned short sBT[192*136];
  int t = threadIdx.x;
  for (int idx = t; idx < 192*16; idx += 256){
    int c = idx >> 4, k8 = idx & 15;
    *(u16x8*)(&sBT[c*136 + k8*8]) = *(const u16x8*)(BT + c*128 + k8*8);
  }
  __syncthreads();
  int w = t >> 6, lane = t & 63;
  int rrow = lane & 15, grp = lane >> 4;
  size_t row0 = (size_t)blockIdx.x*64 + w*16;
  const float* arow = pr + (row0 + rrow)*(size_t)DIMV + grp*8;
  float a[4][8];
  #pragma unroll
  for (int ks = 0; ks < 4; ks++){
    *(f32x4*)(&a[ks][0]) = *(const f32x4*)(arow + ks*32);
    *(f32x4*)(&a[ks][4]) = *(const f32x4*)(arow + ks*32 + 4);
  }
  f32x4 acc[12];
  f32x4 zero = {0.f, 0.f, 0.f, 0.f};
  #pragma unroll
  for (int ct = 0; ct < 12; ct++) acc[ct] = zero;
  #pragma unroll
  for (int ks = 0; ks < 4; ks++){
    bf16x8 af;
    #pragma unroll
    for (int e = 0; e < 8; e++) af[e] = (short)f2bf(a[ks][e]);
    #pragma unroll
    for (int ct = 0; ct < 12; ct++){
      bf16x8 bfr = *(const bf16x8*)(&sBT[(ct*16 + rrow)*136 + ks*32 + grp*8]);
      acc[ct] = MFMA(af, bfr, acc[ct]);
    }
  }
  #pragma unroll
  for (int ct = 0; ct < 12; ct++){
    int col = ct*16 + rrow;
    #pragma unroll
    for (int rg = 0; rg < 4; rg++){
      size_t grow = row0 + grp*4 + rg;
      float v = acc[ct][rg];
      if (col < 64){
        qB[grow*AD + col] = f2bf(v);
      } else {
        int e = col - 64;
        float s = 1.f / (1.f + __expf(-(v + bg[e])));
        gB[grow*DIMV + e] = f2bf(s);
      }
    }
  }
}

// ---------- fused attention core (MFMA), writes bf16 U ----------
__global__ __launch_bounds__(512) void kmain(
    const float* __restrict__ td,
    const unsigned short* __restrict__ qB,
    const unsigned short* __restrict__ leftB, const unsigned short* __restrict__ rightTB,
    const unsigned short* __restrict__ voLT, const unsigned short* __restrict__ voRTT,
    const float* __restrict__ tl, const float* __restrict__ tr,
    const float* __restrict__ gatep,
    unsigned short* __restrict__ U){
  __shared__ __align__(16) char smem[69632];
  float* S = (float*)smem;                    // [16i][16j][32k], strides S_I/S_J
  unsigned short* U1 = (unsigned short*)smem; // [16i][16j][128d], strides U_I/U_J (aliased)
  const int i0 = blockIdx.y*16, j0 = blockIdx.x*16;
  const int t = threadIdx.x, w = t >> 6, lane = t & 63;
  const int n = lane & 15, grp = lane >> 4;
  const float gate = gatep[0];
  const f32x4 zf = {0.f,0.f,0.f,0.f};

  // ---- term1: wave w handles i = 2w, 2w+1 ----
  #pragma unroll
  for (int ii = 0; ii < 2; ii++){
    int i = w*2 + ii;
    const unsigned short* qp = qB + (((size_t)(i0+i)*LL) + j0 + n)*AD + grp*8;
    bf16x8 a0 = *(const bf16x8*)qp;
    bf16x8 a1 = *(const bf16x8*)(qp + 32);
    const unsigned short* lp = leftB + (((size_t)(i0+i)*KK) + n)*AD + grp*8;
    f32x4 acc0 = zf, acc1 = zf;
    acc0 = MFMA(a0, *(const bf16x8*)(lp),            acc0);
    acc0 = MFMA(a1, *(const bf16x8*)(lp + 32),       acc0);
    acc1 = MFMA(a0, *(const bf16x8*)(lp + 16*AD),    acc1);
    acc1 = MFMA(a1, *(const bf16x8*)(lp + 16*AD+32), acc1);
    #pragma unroll
    for (int r2 = 0; r2 < 4; r2++){
      S[i*S_I + (grp*4+r2)*S_J + n]      = acc0[r2];
      S[i*S_I + (grp*4+r2)*S_J + 16 + n] = acc1[r2];
    }
  }
  __syncthreads();
  // ---- term2 + bias: wave w handles j = 2w, 2w+1 ----
  #pragma unroll
  for (int jj = 0; jj < 2; jj++){
    int j = w*2 + jj;
    const unsigned short* qp = qB + (((size_t)(i0+n)*LL) + j0 + j)*AD + grp*8;
    bf16x8 a0 = *(const bf16x8*)qp;
    bf16x8 a1 = *(const bf16x8*)(qp + 32);
    const unsigned short* rp = rightTB + (((size_t)(j0+j)*KK) + n)*AD + grp*8;
    f32x4 acc0 = zf, acc1 = zf;
    acc0 = MFMA(a0, *(const bf16x8*)(rp),            acc0);
    acc0 = MFMA(a1, *(const bf16x8*)(rp + 32),       acc0);
    acc1 = MFMA(a0, *(const bf16x8*)(rp + 16*AD),    acc1);
    acc1 = MFMA(a1, *(const bf16x8*)(rp + 16*AD+32), acc1);
    #pragma unroll
    for (int r2 = 0; r2 < 4; r2++){
      int i = grp*4 + r2;
      float tdv = td[((size_t)(i0+i))*LL + j0 + j];
      #pragma unroll
      for (int nt = 0; nt < 2; nt++){
        int k = nt*16 + n;
        float acc = nt ? acc1[r2] : acc0[r2];
        float tb = tl[(i0+i)*KK + k] + tr[(j0+j)*KK + k] - tdv;
        int idx = i*S_I + j*S_J + k;
        S[idx] = (S[idx] + acc)*0.125f - gate*0.25f*fabsf(tb);
      }
    }
  }
  __syncthreads();
  // ---- softmax: 2 threads per (i,j) pair ----
  {
    int pair = t >> 1, half = t & 1;
    int i = pair >> 4, j = pair & 15;
    float* row = S + i*S_I + j*S_J + half*16;
    float v[16];
    float m = -1e30f;
    #pragma unroll
    for (int kk = 0; kk < 16; kk++){ v[kk] = row[kk]; m = fmaxf(m, v[kk]); }
    m = fmaxf(m, __shfl_xor(m, 1));
    float ss = 0.f;
    #pragma unroll
    for (int kk = 0; kk < 16; kk++){ v[kk] = __expf(v[kk] - m); ss += v[kk]; }
    ss += __shfl_xor(ss, 1);
    float rr = 1.0f / ss;
    #pragma unroll
    for (int kk = 0; kk < 16; kk++) row[kk] = v[kk]*rr;
  }
  __syncthreads();
  // ---- load PV A-frags (attn) before LDS reuse ----
  bf16x8 pa1[2], pa2[2];
  #pragma unroll
  for (int ii = 0; ii < 2; ii++){
    int i = w*2 + ii;
    #pragma unroll
    for (int e = 0; e < 8; e++) pa1[ii][e] = (short)f2bf(S[i*S_I + n*S_J + grp*8 + e]);
    #pragma unroll
    for (int e = 0; e < 8; e++) pa2[ii][e] = (short)f2bf(S[n*S_I + i*S_J + grp*8 + e]);
  }
  __syncthreads();
  // ---- PV1: U1[i][j][d] (bf16) ----
  #pragma unroll
  for (int ii = 0; ii < 2; ii++){
    int i = w*2 + ii;
    #pragma unroll
    for (int nt = 0; nt < 8; nt++){
      bf16x8 bv = *(const bf16x8*)(voLT + (((size_t)(i0+i)*DIMV) + nt*16 + n)*KK + grp*8);
      f32x4 acc = MFMA(pa1[ii], bv, zf);
      #pragma unroll
      for (int r2 = 0; r2 < 4; r2++)
        U1[i*U_I + (grp*4+r2)*U_J + nt*16 + n] = f2bf(acc[r2]);
    }
  }
  __syncthreads();
  // ---- PV2: accumulate into U1 (bf16 RMW) ----
  #pragma unroll
  for (int jj = 0; jj < 2; jj++){
    int j = w*2 + jj;
    #pragma unroll
    for (int nt = 0; nt < 8; nt++){
      bf16x8 bv = *(const bf16x8*)(voRTT + (((size_t)(j0+j)*DIMV) + nt*16 + n)*KK + grp*8);
      f32x4 acc = MFMA(pa2[jj], bv, zf);
      #pragma unroll
      for (int r2 = 0; r2 < 4; r2++){
        int i = grp*4 + r2;
        int d = nt*16 + n;
        int idx = i*U_I + j*U_J + d;
        U1[idx] = f2bf(bf2f(U1[idx]) + acc[r2]);
      }
    }
  }
  __syncthreads();
  // ---- coalesced U dump: 16x16 pairs x 128 d, u16x8 chunks ----
  for (int idx = t; idx < 4096; idx += 512){
    int p = idx >> 4, c = idx & 15;
    int i = p >> 4, j = p & 15;
    u16x8 v = *(const u16x8*)(&U1[i*U_I + j*U_J + c*8]);
    *(u16x8*)(U + (((size_t)(i0+i)*LL) + j0 + j)*DIMV + c*8) = v;
  }
}

// ---------- final: out = pr + g * U (pure streaming) ----------
__global__ __launch_bounds__(256) void kfin(const float* __restrict__ pr,
                     const unsigned short* __restrict__ gB,
                     const unsigned short* __restrict__ U,
                     float* __restrict__ out){
  size_t base = ((size_t)blockIdx.x*256 + threadIdx.x) * 8;
  u16x8 uv = *(const u16x8*)(U + base);
  u16x8 gv = *(const u16x8*)(gB + base);
  f32x4 p0 = *(const f32x4*)(pr + base);
  f32x4 p1 = *(const f32x4*)(pr + base + 4);
  f32x4 o0, o1;
  #pragma unroll
  for (int e = 0; e < 4; e++){
    o0[e] = p0[e] + bf2f((unsigned short)gv[e])   * bf2f((unsigned short)uv[e]);
    o1[e] = p1[e] + bf2f((unsigned short)gv[4+e]) * bf2f((unsigned short)uv[4+e]);
  }
  *(f32x4*)(out + base)     = o0;
  *(f32x4*)(out + base + 4) = o1;
}

extern "C" void kernel_launch(void* const* d_in, const int* in_sizes, int n_in,
                              void* d_out, int out_size, void* d_ws, size_t ws_size,
                              hipStream_t stream){
  const float* pr  = (const float*)d_in[0];
  const float* td  = (const float*)d_in[1];
  const float* tq  = (const float*)d_in[2];
  const float* Wq  = (const float*)d_in[3];
  const float* Wl  = (const float*)d_in[4];
  const float* Wr  = (const float*)d_in[5];
  const float* Wvl = (const float*)d_in[6];
  const float* Wvr = (const float*)d_in[7];
  const float* Wo  = (const float*)d_in[8];
  const float* Wg  = (const float*)d_in[9];
  const float* bg  = (const float*)d_in[10];
  const float* W1  = (const float*)d_in[11];
  const float* b1  = (const float*)d_in[12];
  const float* W2  = (const float*)d_in[13];
  const float* b2  = (const float*)d_in[14];
  const int* anchor = (const int*)d_in[15];
  float* out = (float*)d_out;

  char* ws = (char*)d_ws;
  size_t off = 0;
  auto alloc = [&](size_t bytes)->void*{ void* p = ws + off; off += (bytes + 255) & ~(size_t)255; return p; };
  float* g_gate  = (float*)alloc(4);
  float* g_part  = (float*)alloc(256*4);
  float* g_tl    = (float*)alloc((size_t)LL*KK*4);
  float* g_tr    = (float*)alloc((size_t)LL*KK*4);
  unsigned short* g_BT     = (unsigned short*)alloc((size_t)192*128*2);
  unsigned short* g_left   = (unsigned short*)alloc((size_t)LL*KK*AD*2);
  unsigned short* g_rightT = (unsigned short*)alloc((size_t)LL*KK*AD*2);
  unsigned short* g_voLT   = (unsigned short*)alloc((size_t)LL*DIMV*KK*2);
  unsigned short* g_voRTT  = (unsigned short*)alloc((size_t)LL*DIMV*KK*2);
  unsigned short* g_q      = (unsigned short*)alloc((size_t)LL*LL*AD*2);
  unsigned short* g_g      = (unsigned short*)alloc((size_t)LL*LL*DIMV*2);
  unsigned short* g_U      = (unsigned short*)alloc((size_t)LL*LL*DIMV*2);
  (void)ws_size; (void)in_sizes; (void)n_in; (void)out_size;

  kcov <<<256, 256, 0, stream>>>(td, g_part);
  kgate<<<1,   256, 0, stream>>>(g_part, tq, W1, b1, W2, b2, Wq, Wg, g_gate, g_BT);
  kproj<<<1024,256, 0, stream>>>(pr, td, anchor, Wl, Wr, Wvl, Wvr, Wo,
                                 g_left, g_rightT, g_voLT, g_voRTT, g_tl, g_tr);
  kqg  <<<4096,256, 0, stream>>>(pr, g_BT, bg, g_q, g_g);
  kmain<<<dim3(32,32), 512, 0, stream>>>(td, g_q, g_left, g_rightT,
                                         g_voLT, g_voRTT, g_tl, g_tr, g_gate, g_U);
  kfin <<<16384, 256, 0, stream>>>(pr, g_g, g_U, out);
}